// Round 15
// baseline (280.082 us; speedup 1.0000x reference)
//
#include <hip/hip_runtime.h>
#include <hip/hip_fp16.h>

#define NEG_SLOPE 0.2f
#define BN_EPS 1e-5f

constexpr int D = 64;   // feature dim
constexpr int H = 4;    // heads

typedef _Float16 half4_t __attribute__((ext_vector_type(4)));
typedef _Float16 half8_t __attribute__((ext_vector_type(8)));
typedef float f32x4_t __attribute__((ext_vector_type(4)));
typedef int i32x4 __attribute__((ext_vector_type(4)));  // native vec for nontemporal builtins

// 16-B edge record: {src, pad, w[4]}; w = per-edge softmax numerators (4 heads)
union Rec {
    i32x4 i4;
    struct { int idx; int pad; half4_t w; } f;
};

#define MFMA16(a, b, c) __builtin_amdgcn_mfma_f32_16x16x32_f16(a, b, c, 0, 0, 0)

__device__ inline float lrelu(float v) { return (v >= 0.f) ? v : NEG_SLOPE * v; }

// load 8 consecutive fp32, split into fp16 hi + lo halves (hi+lo ~ fp32)
__device__ inline void split8(const float* p, bool ok, half8_t& hi, half8_t& lo) {
    float f[8];
    if (ok) {
        float4 a = *(const float4*)p;
        float4 b = *(const float4*)(p + 4);
        f[0] = a.x; f[1] = a.y; f[2] = a.z; f[3] = a.w;
        f[4] = b.x; f[5] = b.y; f[6] = b.z; f[7] = b.w;
    } else {
        #pragma unroll
        for (int j = 0; j < 8; j++) f[j] = 0.f;
    }
    #pragma unroll
    for (int j = 0; j < 8; j++) {
        _Float16 h = (_Float16)f[j];
        hi[j] = h;
        lo[j] = (_Float16)(f[j] - (float)h);
    }
}

// Fused MFMA node kernel, 32 nodes/block, with a FIRE-AND-FORGET histogram
// prelude: atomicAdd return discarded -> no waitcnt on the atomic response,
// the prelude is pure issue throughput (the dependent-rank chain was ~55us
// of R14's k_node). deg/sums/gcount pre-zeroed by hipMemsetAsync.
// x1 = prelu(x @ W_lin^T + b_lin); h = x1 @ W_gat^T (split-fp16 MFMA ~ fp32);
// h stored fp16 layout [n][d][head]; attention dots from accumulators.
__global__ __launch_bounds__(256) void k_node(
    const float* __restrict__ x,
    const float* __restrict__ W_lin, const float* __restrict__ b_lin,
    const float* __restrict__ prelu_w, const float* __restrict__ W_gat,
    const float* __restrict__ att_src, const float* __restrict__ att_dst,
    _Float16* __restrict__ hh, float* __restrict__ asrc_ws,
    float* __restrict__ adst_ws, const int* __restrict__ ei,
    int* __restrict__ deg, int N, int E)
{
    __shared__ _Float16 h_lds[32 * 264];   // 16.5 KB, rows padded to 264 halves
    __shared__ _Float16 x1hi[32 * 72];     // 4.5 KB, row-padded (72 halves=144B)
    __shared__ _Float16 x1lo[32 * 72];

    const int t = threadIdx.x;
    const int w = t >> 6;    // wave id == head
    const int l = t & 63;
    const int li = l & 15;
    const int lq = l >> 4;
    const int base = blockIdx.x * 32;
    const int nvalid = min(32, N - base);

    // ---- fire-and-forget hist prelude (return discarded -> no latency chain)
    {
        const int stride = gridDim.x * 256;
        for (int e = blockIdx.x * 256 + t; e < E; e += stride) {
            atomicAdd(&deg[ei[E + e]], 1);
        }
    }

    // ---- stage A: MFMA x @ W_lin^T for cols 16w..16w+15, 2 m-tiles ----
    f32x4_t accA[2] = {};
    {
        half8_t blh[2], bll[2];
        const int n = 16 * w + li;
        #pragma unroll
        for (int ks = 0; ks < 2; ks++)
            split8(W_lin + n * 64 + 32 * ks + 8 * lq, true, blh[ks], bll[ks]);
        #pragma unroll
        for (int mt = 0; mt < 2; mt++) {
            const int row = base + 16 * mt + li;
            const bool ok = row < N;
            #pragma unroll
            for (int ks = 0; ks < 2; ks++) {
                half8_t ah, al;
                split8(x + (size_t)row * 64 + 32 * ks + 8 * lq, ok, ah, al);
                accA[mt] = MFMA16(ah, blh[ks], accA[mt]);
                accA[mt] = MFMA16(al, blh[ks], accA[mt]);
                accA[mt] = MFMA16(ah, bll[ks], accA[mt]);
            }
        }
    }
    // epilogue A: +bias, prelu, split to fp16 hi/lo in LDS
    {
        const int n = 16 * w + li;
        const float bl = b_lin[n];
        const float pw = prelu_w[n];
        #pragma unroll
        for (int mt = 0; mt < 2; mt++) {
            #pragma unroll
            for (int r = 0; r < 4; r++) {
                const int m = 16 * mt + lq * 4 + r;
                float v = accA[mt][r] + bl;
                v = (v >= 0.f) ? v : pw * v;
                _Float16 hi = (_Float16)v;
                x1hi[m * 72 + n] = hi;
                x1lo[m * 72 + n] = (_Float16)(v - (float)hi);
            }
        }
    }
    __syncthreads();

    // ---- stage B: MFMA x1 @ W_gat^T for cols 64w..64w+63, 2 m-tiles ----
    half8_t xah[2][2], xal[2][2];
    #pragma unroll
    for (int mt = 0; mt < 2; mt++) {
        #pragma unroll
        for (int ks = 0; ks < 2; ks++) {
            const int off = (16 * mt + li) * 72 + 32 * ks + 8 * lq;
            xah[mt][ks] = *(const half8_t*)(&x1hi[off]);
            xal[mt][ks] = *(const half8_t*)(&x1lo[off]);
        }
    }
    f32x4_t accB[2][4] = {};
    #pragma unroll
    for (int nt = 0; nt < 4; nt++) {
        half8_t wh[2], wl[2];
        const int c = 64 * w + 16 * nt + li;
        #pragma unroll
        for (int ks = 0; ks < 2; ks++)
            split8(W_gat + (size_t)c * 64 + 32 * ks + 8 * lq, true, wh[ks], wl[ks]);
        #pragma unroll
        for (int mt = 0; mt < 2; mt++) {
            #pragma unroll
            for (int ks = 0; ks < 2; ks++) {
                accB[mt][nt] = MFMA16(xah[mt][ks], wh[ks], accB[mt][nt]);
                accB[mt][nt] = MFMA16(xal[mt][ks], wh[ks], accB[mt][nt]);
                accB[mt][nt] = MFMA16(xah[mt][ks], wl[ks], accB[mt][nt]);
            }
        }
    }

    // ---- attention dots from registers: a[n][w] = sum_d h[n][w][d]*att[w][d]
    {
        float asv[4], adv[4];
        #pragma unroll
        for (int nt = 0; nt < 4; nt++) {
            const int c = 64 * w + 16 * nt + li;
            asv[nt] = att_src[c];
            adv[nt] = att_dst[c];
        }
        #pragma unroll
        for (int mt = 0; mt < 2; mt++) {
            #pragma unroll
            for (int r = 0; r < 4; r++) {
                float s = 0.f, dsum = 0.f;
                #pragma unroll
                for (int nt = 0; nt < 4; nt++) {
                    s += accB[mt][nt][r] * asv[nt];
                    dsum += accB[mt][nt][r] * adv[nt];
                }
                #pragma unroll
                for (int off = 1; off < 16; off <<= 1) {
                    s += __shfl_xor(s, off, 64);
                    dsum += __shfl_xor(dsum, off, 64);
                }
                if (li == 0) {
                    const int m = 16 * mt + lq * 4 + r;
                    if (m < nvalid) {
                        asrc_ws[(size_t)(base + m) * H + w] = s;
                        adst_ws[(size_t)(base + m) * H + w] = dsum;
                    }
                }
            }
        }
    }

    // ---- h -> LDS in padded [m][264] layout, then coalesced global write ----
    #pragma unroll
    for (int mt = 0; mt < 2; mt++) {
        #pragma unroll
        for (int nt = 0; nt < 4; nt++) {
            #pragma unroll
            for (int r = 0; r < 4; r++) {
                const int m = 16 * mt + lq * 4 + r;
                const int d = 16 * nt + li;
                h_lds[m * 264 + d * 4 + w] = (_Float16)accB[mt][nt][r];
            }
        }
    }
    __syncthreads();
    {
        const int chunks = nvalid * 32;  // 8 halves (16B) per chunk
        const uint4* src = (const uint4*)h_lds;
        uint4* dst = (uint4*)(hh + (size_t)base * 256);
        for (int i = t; i < chunks; i += 256) {
            int row = i >> 5;
            int col = i & 31;
            dst[i] = src[row * 33 + col];  // padded row = 33 uint4
        }
    }
}

// offsets: per-block exclusive scan + one atomicAdd for the block's recs base;
// writes both offs (for k_agg) and cur (running cursor for k_fill).
__global__ __launch_bounds__(256) void k_offsets(const int* __restrict__ deg,
                                                 int* __restrict__ gcount,
                                                 int* __restrict__ offs,
                                                 int* __restrict__ cur, int N) {
    __shared__ int sm[256];
    __shared__ int sbase;
    int t = threadIdx.x;
    int idx = blockIdx.x * 256 + t;
    int v = (idx < N) ? deg[idx] : 0;
    sm[t] = v;
    __syncthreads();
    for (int off = 1; off < 256; off <<= 1) {
        int w = (t >= off) ? sm[t - off] : 0;
        __syncthreads();
        sm[t] += w;
        __syncthreads();
    }
    if (t == 255) sbase = atomicAdd(gcount, sm[255]);
    __syncthreads();
    if (idx < N) {
        int e = sbase + sm[t] - v;  // exclusive within block + block base
        offs[idx] = e;
        cur[idx] = e;
    }
}

// permute-scatter: pos = atomicAdd(&cur[d],1) (order within a dst bucket is
// irrelevant). Computes w from the L2-resident asrc/adst tables. Plain 16-B
// store (L2 coalescing of 4 records/line beats NT — measured R5 vs R8).
__global__ __launch_bounds__(256) void k_fill(const int* __restrict__ ei,
                                              int* __restrict__ cur,
                                              const float* __restrict__ asrc,
                                              const float* __restrict__ adst,
                                              i32x4* __restrict__ recs, int E) {
    int e = blockIdx.x * 256 + threadIdx.x;
    if (e >= E) return;
    int s = ei[e];
    int d = ei[E + e];
    int pos = atomicAdd(&cur[d], 1);
    float4 a = *(const float4*)(asrc + (size_t)s * H);
    float4 b = *(const float4*)(adst + (size_t)d * H);
    Rec r;
    r.f.idx = s;
    r.f.pad = 0;
    r.f.w[0] = (_Float16)__expf(lrelu(a.x + b.x));
    r.f.w[1] = (_Float16)__expf(lrelu(a.y + b.y));
    r.f.w[2] = (_Float16)__expf(lrelu(a.z + b.z));
    r.f.w[3] = (_Float16)__expf(lrelu(a.w + b.w));
    recs[pos] = r.i4;
}

// ---- fused softmax + aggregation: one wave per dst node (R5 best form) ----
__global__ __launch_bounds__(256) void k_agg(
    const float* __restrict__ asrc, const float* __restrict__ adst,
    const int* __restrict__ offs, const int* __restrict__ deg,
    const i32x4* __restrict__ recs, const half4_t* __restrict__ hh,
    float* __restrict__ out, int N)
{
    int wid = (blockIdx.x * 256 + threadIdx.x) >> 6;
    int lane = threadIdx.x & 63;
    if (wid >= N) return;
    const int i = wid;

    float4 b = *(const float4*)(adst + (size_t)i * H);
    float4 a0 = *(const float4*)(asrc + (size_t)i * H);
    float ws0 = __expf(lrelu(a0.x + b.x));
    float ws1 = __expf(lrelu(a0.y + b.y));
    float ws2 = __expf(lrelu(a0.z + b.z));
    float ws3 = __expf(lrelu(a0.w + b.w));

    const int beg = offs[i];
    const int dg = deg[i];

    // self-loop contribution
    float den0 = ws0, den1 = ws1, den2 = ws2, den3 = ws3;
    float acc0, acc1, acc2, acc3;
    {
        half4_t hv = hh[(size_t)i * D + lane];
        acc0 = ws0 * (float)hv[0];
        acc1 = ws1 * (float)hv[1];
        acc2 = ws2 * (float)hv[2];
        acc3 = ws3 * (float)hv[3];
    }
    int k = 0;
    for (; k + 4 <= dg; k += 4) {
        Rec r0, r1, r2, r3;
        r0.i4 = recs[beg + k];
        r1.i4 = recs[beg + k + 1];
        r2.i4 = recs[beg + k + 2];
        r3.i4 = recs[beg + k + 3];
        half4_t h0 = hh[(size_t)r0.f.idx * D + lane];
        half4_t h1 = hh[(size_t)r1.f.idx * D + lane];
        half4_t h2 = hh[(size_t)r2.f.idx * D + lane];
        half4_t h3 = hh[(size_t)r3.f.idx * D + lane];
        float w00 = (float)r0.f.w[0], w01 = (float)r0.f.w[1],
              w02 = (float)r0.f.w[2], w03 = (float)r0.f.w[3];
        float w10 = (float)r1.f.w[0], w11 = (float)r1.f.w[1],
              w12 = (float)r1.f.w[2], w13 = (float)r1.f.w[3];
        float w20 = (float)r2.f.w[0], w21 = (float)r2.f.w[1],
              w22 = (float)r2.f.w[2], w23 = (float)r2.f.w[3];
        float w30 = (float)r3.f.w[0], w31 = (float)r3.f.w[1],
              w32 = (float)r3.f.w[2], w33 = (float)r3.f.w[3];
        den0 += w00 + w10 + w20 + w30;
        den1 += w01 + w11 + w21 + w31;
        den2 += w02 + w12 + w22 + w32;
        den3 += w03 + w13 + w23 + w33;
        acc0 += w00 * (float)h0[0] + w10 * (float)h1[0] +
                w20 * (float)h2[0] + w30 * (float)h3[0];
        acc1 += w01 * (float)h0[1] + w11 * (float)h1[1] +
                w21 * (float)h2[1] + w31 * (float)h3[1];
        acc2 += w02 * (float)h0[2] + w12 * (float)h1[2] +
                w22 * (float)h2[2] + w32 * (float)h3[2];
        acc3 += w03 * (float)h0[3] + w13 * (float)h1[3] +
                w23 * (float)h2[3] + w33 * (float)h3[3];
    }
    for (; k < dg; k++) {
        Rec r;
        r.i4 = recs[beg + k];
        half4_t hv = hh[(size_t)r.f.idx * D + lane];
        float w0 = (float)r.f.w[0], w1 = (float)r.f.w[1];
        float w2 = (float)r.f.w[2], w3 = (float)r.f.w[3];
        den0 += w0; den1 += w1; den2 += w2; den3 += w3;
        acc0 += w0 * (float)hv[0];
        acc1 += w1 * (float)hv[1];
        acc2 += w2 * (float)hv[2];
        acc3 += w3 * (float)hv[3];
    }

    out[(size_t)i * D + lane] =
        0.25f * (acc0 / den0 + acc1 / den1 + acc2 / den2 + acc3 / den3);
}

// BN stats: per-channel sum & sumsq (channel = idx & 63)
__global__ __launch_bounds__(256) void k_bn_stats(const float* __restrict__ out,
                                                  float* __restrict__ sums,
                                                  int total) {
    const int t = threadIdx.x;
    const int stride = gridDim.x * 256;
    float s = 0.f, sq = 0.f;
    for (int idx = blockIdx.x * 256 + t; idx < total; idx += stride) {
        float v = out[idx];
        s += v;
        sq += v * v;
    }
    __shared__ float ls[256], lq[256];
    ls[t] = s;
    lq[t] = sq;
    __syncthreads();
    if (t < 64) {
        s = ls[t] + ls[t + 64] + ls[t + 128] + ls[t + 192];
        sq = lq[t] + lq[t + 64] + lq[t + 128] + lq[t + 192];
        atomicAdd(&sums[t], s);
        atomicAdd(&sums[64 + t], sq);
    }
}

__global__ __launch_bounds__(256) void k_bn_apply(float* __restrict__ out,
                                                  const float* __restrict__ sums,
                                                  const float* __restrict__ gamma,
                                                  const float* __restrict__ beta,
                                                  int total, float invN) {
    int idx = blockIdx.x * 256 + threadIdx.x;
    if (idx >= total) return;
    int c = idx & 63;
    float mean = sums[c] * invN;
    float var = sums[64 + c] * invN - mean * mean;
    float y = gamma[c] * (out[idx] - mean) * rsqrtf(var + BN_EPS) + beta[c];
    out[idx] = fmaxf(y, 0.f);
}

extern "C" void kernel_launch(void* const* d_in, const int* in_sizes, int n_in,
                              void* d_out, int out_size, void* d_ws, size_t ws_size,
                              hipStream_t stream) {
    const float* x       = (const float*)d_in[0];
    const int*   ei      = (const int*)d_in[1];
    const float* W_lin   = (const float*)d_in[2];
    const float* b_lin   = (const float*)d_in[3];
    const float* prelu_w = (const float*)d_in[4];
    const float* W_gat   = (const float*)d_in[5];
    const float* att_src = (const float*)d_in[6];
    const float* att_dst = (const float*)d_in[7];
    // d_in[8] = gat_bias: constant per-channel shift cancelled exactly by BN
    // mean-subtraction -> skipped.
    const float* bn_gamma = (const float*)d_in[9];
    const float* bn_beta  = (const float*)d_in[10];
    float* out = (float*)d_out;

    const int N = in_sizes[0] / D;
    const int E = in_sizes[1] / 2;

    // workspace carve-up (all chunk sizes multiples of 16B).
    // sums + deg + gcount are CONTIGUOUS so one hipMemsetAsync zeroes all.
    char* wp = (char*)d_ws;
    _Float16* hh = (_Float16*)wp;      wp += (size_t)N * D * H * sizeof(_Float16);
    float* asrc  = (float*)wp;          wp += (size_t)N * H * sizeof(float);
    float* adst  = (float*)wp;          wp += (size_t)N * H * sizeof(float);
    char* zero_base = wp;
    float* sums  = (float*)wp;          wp += 2 * D * sizeof(float);
    int* deg     = (int*)wp;            wp += (size_t)N * sizeof(int);
    int* gcount  = (int*)wp;            wp += 4 * sizeof(int);
    size_t zero_bytes = (size_t)(wp - zero_base);
    int* offs    = (int*)wp;            wp += (size_t)N * sizeof(int);
    int* cur     = (int*)wp;            wp += (size_t)N * sizeof(int);
    i32x4* recs  = (i32x4*)wp;          wp += ((size_t)E + 4) * sizeof(i32x4);
    (void)ws_size; (void)n_in; (void)out_size;

    const int total = N * D;
    const int NB = (N + 255) / 256;

    hipMemsetAsync(zero_base, 0, zero_bytes, stream);
    hipLaunchKernelGGL(k_node, dim3((N + 31) / 32), dim3(256), 0, stream,
                       x, W_lin, b_lin, prelu_w, W_gat, att_src, att_dst,
                       hh, asrc, adst, ei, deg, N, E);
    hipLaunchKernelGGL(k_offsets, dim3(NB), dim3(256), 0, stream,
                       deg, gcount, offs, cur, N);
    hipLaunchKernelGGL(k_fill, dim3((E + 255) / 256), dim3(256), 0, stream,
                       ei, cur, asrc, adst, recs, E);
    hipLaunchKernelGGL(k_agg, dim3((N + 3) / 4), dim3(256), 0, stream,
                       asrc, adst, offs, deg, recs, (const half4_t*)hh, out, N);
    hipLaunchKernelGGL(k_bn_stats, dim3(1024), dim3(256), 0, stream,
                       out, sums, total);
    hipLaunchKernelGGL(k_bn_apply, dim3((total + 255) / 256), dim3(256), 0, stream,
                       out, sums, bn_gamma, bn_beta, total, 1.f / (float)N);
}

// Round 16
// 267.717 us; speedup vs baseline: 1.0462x; 1.0462x over previous
//
#include <hip/hip_runtime.h>
#include <hip/hip_fp16.h>

#define NEG_SLOPE 0.2f
#define BN_EPS 1e-5f

constexpr int D = 64;   // feature dim
constexpr int H = 4;    // heads

typedef _Float16 half4_t __attribute__((ext_vector_type(4)));
typedef _Float16 half8_t __attribute__((ext_vector_type(8)));
typedef float f32x4_t __attribute__((ext_vector_type(4)));
typedef int i32x4 __attribute__((ext_vector_type(4)));  // native vec for nontemporal builtins

// 16-B edge record: {src, pad, w[4]}; w = per-edge softmax numerators (4 heads)
union Rec {
    i32x4 i4;
    struct { int idx; int pad; half4_t w; } f;
};

#define MFMA16(a, b, c) __builtin_amdgcn_mfma_f32_16x16x32_f16(a, b, c, 0, 0, 0)

__device__ inline float lrelu(float v) { return (v >= 0.f) ? v : NEG_SLOPE * v; }

// load 8 consecutive fp32, split into fp16 hi + lo halves (hi+lo ~ fp32)
__device__ inline void split8(const float* p, bool ok, half8_t& hi, half8_t& lo) {
    float f[8];
    if (ok) {
        float4 a = *(const float4*)p;
        float4 b = *(const float4*)(p + 4);
        f[0] = a.x; f[1] = a.y; f[2] = a.z; f[3] = a.w;
        f[4] = b.x; f[5] = b.y; f[6] = b.z; f[7] = b.w;
    } else {
        #pragma unroll
        for (int j = 0; j < 8; j++) f[j] = 0.f;
    }
    #pragma unroll
    for (int j = 0; j < 8; j++) {
        _Float16 h = (_Float16)f[j];
        hi[j] = h;
        lo[j] = (_Float16)(f[j] - (float)h);
    }
}

// Fused MFMA node kernel, 32 nodes/block. Hist+rank prelude is SPLIT into
// phases so the atomic-return latency hides behind stage-A MFMA work:
//   (1) load edge dsts, issue both atomicAdds (independent, both in flight)
//   (2) stage A (dozens of VMEM loads + MFMAs)
//   (3) store the rank values (returns long since arrived -> free waitcnt)
// deg8/sums/gcount pre-zeroed by hipMemsetAsync. XCD-privatized deg8 slices
// (p = (e>>8)&7). x1 = prelu(x @ W_lin^T + b_lin); h = x1 @ W_gat^T
// (split-fp16 MFMA ~ fp32); h stored fp16 [n][d][head]; att dots from regs.
__global__ __launch_bounds__(256) void k_node(
    const float* __restrict__ x,
    const float* __restrict__ W_lin, const float* __restrict__ b_lin,
    const float* __restrict__ prelu_w, const float* __restrict__ W_gat,
    const float* __restrict__ att_src, const float* __restrict__ att_dst,
    _Float16* __restrict__ hh, float* __restrict__ asrc_ws,
    float* __restrict__ adst_ws, const int* __restrict__ ei,
    int* __restrict__ deg8, int* __restrict__ rank, int N, int E)
{
    __shared__ _Float16 h_lds[32 * 264];   // 16.5 KB, rows padded to 264 halves
    __shared__ _Float16 x1hi[32 * 72];     // 4.5 KB, row-padded (72 halves=144B)
    __shared__ _Float16 x1lo[32 * 72];

    const int t = threadIdx.x;
    const int w = t >> 6;    // wave id == head
    const int l = t & 63;
    const int li = l & 15;
    const int lq = l >> 4;
    const int base = blockIdx.x * 32;
    const int nvalid = min(32, N - base);

    // ---- prelude phase 1: issue both rank-atomics (independent chains) ----
    const int nthreads = gridDim.x * 256;
    const int e0 = blockIdx.x * 256 + t;
    const int e1 = e0 + nthreads;
    const bool v0 = e0 < E;
    const bool v1 = e1 < E;
    int r0v = 0, r1v = 0;
    {
        int d0 = 0, d1 = 0;
        if (v0) d0 = ei[E + e0];
        if (v1) d1 = ei[E + e1];
        if (v0) r0v = atomicAdd(&deg8[((e0 >> 8) & 7) * N + d0], 1);
        if (v1) r1v = atomicAdd(&deg8[((e1 >> 8) & 7) * N + d1], 1);
    }

    // ---- stage A: MFMA x @ W_lin^T for cols 16w..16w+15, 2 m-tiles ----
    f32x4_t accA[2] = {};
    {
        half8_t blh[2], bll[2];
        const int n = 16 * w + li;
        #pragma unroll
        for (int ks = 0; ks < 2; ks++)
            split8(W_lin + n * 64 + 32 * ks + 8 * lq, true, blh[ks], bll[ks]);
        #pragma unroll
        for (int mt = 0; mt < 2; mt++) {
            const int row = base + 16 * mt + li;
            const bool ok = row < N;
            #pragma unroll
            for (int ks = 0; ks < 2; ks++) {
                half8_t ah, al;
                split8(x + (size_t)row * 64 + 32 * ks + 8 * lq, ok, ah, al);
                accA[mt] = MFMA16(ah, blh[ks], accA[mt]);
                accA[mt] = MFMA16(al, blh[ks], accA[mt]);
                accA[mt] = MFMA16(ah, bll[ks], accA[mt]);
            }
        }
    }

    // ---- prelude phase 3: store ranks (atomic returns arrived long ago) ----
    if (v0) rank[e0] = r0v;
    if (v1) rank[e1] = r1v;

    // epilogue A: +bias, prelu, split to fp16 hi/lo in LDS
    {
        const int n = 16 * w + li;
        const float bl = b_lin[n];
        const float pw = prelu_w[n];
        #pragma unroll
        for (int mt = 0; mt < 2; mt++) {
            #pragma unroll
            for (int r = 0; r < 4; r++) {
                const int m = 16 * mt + lq * 4 + r;
                float v = accA[mt][r] + bl;
                v = (v >= 0.f) ? v : pw * v;
                _Float16 hi = (_Float16)v;
                x1hi[m * 72 + n] = hi;
                x1lo[m * 72 + n] = (_Float16)(v - (float)hi);
            }
        }
    }
    __syncthreads();

    // ---- stage B: MFMA x1 @ W_gat^T for cols 64w..64w+63, 2 m-tiles ----
    half8_t xah[2][2], xal[2][2];
    #pragma unroll
    for (int mt = 0; mt < 2; mt++) {
        #pragma unroll
        for (int ks = 0; ks < 2; ks++) {
            const int off = (16 * mt + li) * 72 + 32 * ks + 8 * lq;
            xah[mt][ks] = *(const half8_t*)(&x1hi[off]);
            xal[mt][ks] = *(const half8_t*)(&x1lo[off]);
        }
    }
    f32x4_t accB[2][4] = {};
    #pragma unroll
    for (int nt = 0; nt < 4; nt++) {
        half8_t wh[2], wl[2];
        const int c = 64 * w + 16 * nt + li;
        #pragma unroll
        for (int ks = 0; ks < 2; ks++)
            split8(W_gat + (size_t)c * 64 + 32 * ks + 8 * lq, true, wh[ks], wl[ks]);
        #pragma unroll
        for (int mt = 0; mt < 2; mt++) {
            #pragma unroll
            for (int ks = 0; ks < 2; ks++) {
                accB[mt][nt] = MFMA16(xah[mt][ks], wh[ks], accB[mt][nt]);
                accB[mt][nt] = MFMA16(xal[mt][ks], wh[ks], accB[mt][nt]);
                accB[mt][nt] = MFMA16(xah[mt][ks], wl[ks], accB[mt][nt]);
            }
        }
    }

    // ---- attention dots from registers: a[n][w] = sum_d h[n][w][d]*att[w][d]
    {
        float asv[4], adv[4];
        #pragma unroll
        for (int nt = 0; nt < 4; nt++) {
            const int c = 64 * w + 16 * nt + li;
            asv[nt] = att_src[c];
            adv[nt] = att_dst[c];
        }
        #pragma unroll
        for (int mt = 0; mt < 2; mt++) {
            #pragma unroll
            for (int r = 0; r < 4; r++) {
                float s = 0.f, dsum = 0.f;
                #pragma unroll
                for (int nt = 0; nt < 4; nt++) {
                    s += accB[mt][nt][r] * asv[nt];
                    dsum += accB[mt][nt][r] * adv[nt];
                }
                #pragma unroll
                for (int off = 1; off < 16; off <<= 1) {
                    s += __shfl_xor(s, off, 64);
                    dsum += __shfl_xor(dsum, off, 64);
                }
                if (li == 0) {
                    const int m = 16 * mt + lq * 4 + r;
                    if (m < nvalid) {
                        asrc_ws[(size_t)(base + m) * H + w] = s;
                        adst_ws[(size_t)(base + m) * H + w] = dsum;
                    }
                }
            }
        }
    }

    // ---- h -> LDS in padded [m][264] layout, then coalesced global write ----
    #pragma unroll
    for (int mt = 0; mt < 2; mt++) {
        #pragma unroll
        for (int nt = 0; nt < 4; nt++) {
            #pragma unroll
            for (int r = 0; r < 4; r++) {
                const int m = 16 * mt + lq * 4 + r;
                const int d = 16 * nt + li;
                h_lds[m * 264 + d * 4 + w] = (_Float16)accB[mt][nt][r];
            }
        }
    }
    __syncthreads();
    {
        const int chunks = nvalid * 32;  // 8 halves (16B) per chunk
        const uint4* src = (const uint4*)h_lds;
        uint4* dst = (uint4*)(hh + (size_t)base * 256);
        for (int i = t; i < chunks; i += 256) {
            int row = i >> 5;
            int col = i & 31;
            dst[i] = src[row * 33 + col];  // padded row = 33 uint4
        }
    }
}

// offsets: fold the 8 slices (exclusive prefix over p -> pref8, total -> deg),
// then per-block exclusive scan + one atomicAdd for the block's recs base.
__global__ __launch_bounds__(256) void k_offsets(const int* __restrict__ deg8,
                                                 int* __restrict__ pref8,
                                                 int* __restrict__ deg,
                                                 int* __restrict__ gcount,
                                                 int* __restrict__ offs, int N) {
    __shared__ int sm[256];
    __shared__ int sbase;
    int t = threadIdx.x;
    int idx = blockIdx.x * 256 + t;
    int v = 0;
    if (idx < N) {
        #pragma unroll
        for (int p = 0; p < 8; p++) {
            int c = deg8[p * N + idx];
            pref8[p * N + idx] = v;
            v += c;
        }
        deg[idx] = v;
    }
    sm[t] = v;
    __syncthreads();
    for (int off = 1; off < 256; off <<= 1) {
        int w = (t >= off) ? sm[t - off] : 0;
        __syncthreads();
        sm[t] += w;
        __syncthreads();
    }
    if (t == 255) sbase = atomicAdd(gcount, sm[255]);
    __syncthreads();
    if (idx < N) offs[idx] = sbase + sm[t] - v;  // exclusive within block + base
}

// atomic-free permute-scatter: pos = offs[dst] + pref8[p][dst] + rank.
// p derived from e the same way as the k_node prelude (e0/e1 = tid, tid+T).
// Computes w from the L2-resident asrc/adst tables. Plain 16-B store.
__global__ __launch_bounds__(256) void k_fill(const int* __restrict__ ei,
                                              const int* __restrict__ offs,
                                              const int* __restrict__ pref8,
                                              const int* __restrict__ rank,
                                              const float* __restrict__ asrc,
                                              const float* __restrict__ adst,
                                              i32x4* __restrict__ recs,
                                              int N, int E) {
    int e = blockIdx.x * 256 + threadIdx.x;
    if (e >= E) return;
    int s = ei[e];
    int d = ei[E + e];
    int p = (e >> 8) & 7;
    int r0 = rank[e];
    int pos = offs[d] + pref8[p * N + d] + r0;
    float4 a = *(const float4*)(asrc + (size_t)s * H);
    float4 b = *(const float4*)(adst + (size_t)d * H);
    Rec r;
    r.f.idx = s;
    r.f.pad = 0;
    r.f.w[0] = (_Float16)__expf(lrelu(a.x + b.x));
    r.f.w[1] = (_Float16)__expf(lrelu(a.y + b.y));
    r.f.w[2] = (_Float16)__expf(lrelu(a.z + b.z));
    r.f.w[3] = (_Float16)__expf(lrelu(a.w + b.w));
    recs[pos] = r.i4;
}

// ---- fused softmax + aggregation: one wave per dst node (R5 best form) ----
__global__ __launch_bounds__(256) void k_agg(
    const float* __restrict__ asrc, const float* __restrict__ adst,
    const int* __restrict__ offs, const int* __restrict__ deg,
    const i32x4* __restrict__ recs, const half4_t* __restrict__ hh,
    float* __restrict__ out, int N)
{
    int wid = (blockIdx.x * 256 + threadIdx.x) >> 6;
    int lane = threadIdx.x & 63;
    if (wid >= N) return;
    const int i = wid;

    float4 b = *(const float4*)(adst + (size_t)i * H);
    float4 a0 = *(const float4*)(asrc + (size_t)i * H);
    float ws0 = __expf(lrelu(a0.x + b.x));
    float ws1 = __expf(lrelu(a0.y + b.y));
    float ws2 = __expf(lrelu(a0.z + b.z));
    float ws3 = __expf(lrelu(a0.w + b.w));

    const int beg = offs[i];
    const int dg = deg[i];

    // self-loop contribution
    float den0 = ws0, den1 = ws1, den2 = ws2, den3 = ws3;
    float acc0, acc1, acc2, acc3;
    {
        half4_t hv = hh[(size_t)i * D + lane];
        acc0 = ws0 * (float)hv[0];
        acc1 = ws1 * (float)hv[1];
        acc2 = ws2 * (float)hv[2];
        acc3 = ws3 * (float)hv[3];
    }
    int k = 0;
    for (; k + 4 <= dg; k += 4) {
        Rec r0, r1, r2, r3;
        r0.i4 = recs[beg + k];
        r1.i4 = recs[beg + k + 1];
        r2.i4 = recs[beg + k + 2];
        r3.i4 = recs[beg + k + 3];
        half4_t h0 = hh[(size_t)r0.f.idx * D + lane];
        half4_t h1 = hh[(size_t)r1.f.idx * D + lane];
        half4_t h2 = hh[(size_t)r2.f.idx * D + lane];
        half4_t h3 = hh[(size_t)r3.f.idx * D + lane];
        float w00 = (float)r0.f.w[0], w01 = (float)r0.f.w[1],
              w02 = (float)r0.f.w[2], w03 = (float)r0.f.w[3];
        float w10 = (float)r1.f.w[0], w11 = (float)r1.f.w[1],
              w12 = (float)r1.f.w[2], w13 = (float)r1.f.w[3];
        float w20 = (float)r2.f.w[0], w21 = (float)r2.f.w[1],
              w22 = (float)r2.f.w[2], w23 = (float)r2.f.w[3];
        float w30 = (float)r3.f.w[0], w31 = (float)r3.f.w[1],
              w32 = (float)r3.f.w[2], w33 = (float)r3.f.w[3];
        den0 += w00 + w10 + w20 + w30;
        den1 += w01 + w11 + w21 + w31;
        den2 += w02 + w12 + w22 + w32;
        den3 += w03 + w13 + w23 + w33;
        acc0 += w00 * (float)h0[0] + w10 * (float)h1[0] +
                w20 * (float)h2[0] + w30 * (float)h3[0];
        acc1 += w01 * (float)h0[1] + w11 * (float)h1[1] +
                w21 * (float)h2[1] + w31 * (float)h3[1];
        acc2 += w02 * (float)h0[2] + w12 * (float)h1[2] +
                w22 * (float)h2[2] + w32 * (float)h3[2];
        acc3 += w03 * (float)h0[3] + w13 * (float)h1[3] +
                w23 * (float)h2[3] + w33 * (float)h3[3];
    }
    for (; k < dg; k++) {
        Rec r;
        r.i4 = recs[beg + k];
        half4_t hv = hh[(size_t)r.f.idx * D + lane];
        float w0 = (float)r.f.w[0], w1 = (float)r.f.w[1];
        float w2 = (float)r.f.w[2], w3 = (float)r.f.w[3];
        den0 += w0; den1 += w1; den2 += w2; den3 += w3;
        acc0 += w0 * (float)hv[0];
        acc1 += w1 * (float)hv[1];
        acc2 += w2 * (float)hv[2];
        acc3 += w3 * (float)hv[3];
    }

    out[(size_t)i * D + lane] =
        0.25f * (acc0 / den0 + acc1 / den1 + acc2 / den2 + acc3 / den3);
}

// BN stats: per-channel sum & sumsq (channel = idx & 63)
__global__ __launch_bounds__(256) void k_bn_stats(const float* __restrict__ out,
                                                  float* __restrict__ sums,
                                                  int total) {
    const int t = threadIdx.x;
    const int stride = gridDim.x * 256;
    float s = 0.f, sq = 0.f;
    for (int idx = blockIdx.x * 256 + t; idx < total; idx += stride) {
        float v = out[idx];
        s += v;
        sq += v * v;
    }
    __shared__ float ls[256], lq[256];
    ls[t] = s;
    lq[t] = sq;
    __syncthreads();
    if (t < 64) {
        s = ls[t] + ls[t + 64] + ls[t + 128] + ls[t + 192];
        sq = lq[t] + lq[t + 64] + lq[t + 128] + lq[t + 192];
        atomicAdd(&sums[t], s);
        atomicAdd(&sums[64 + t], sq);
    }
}

__global__ __launch_bounds__(256) void k_bn_apply(float* __restrict__ out,
                                                  const float* __restrict__ sums,
                                                  const float* __restrict__ gamma,
                                                  const float* __restrict__ beta,
                                                  int total, float invN) {
    int idx = blockIdx.x * 256 + threadIdx.x;
    if (idx >= total) return;
    int c = idx & 63;
    float mean = sums[c] * invN;
    float var = sums[64 + c] * invN - mean * mean;
    float y = gamma[c] * (out[idx] - mean) * rsqrtf(var + BN_EPS) + beta[c];
    out[idx] = fmaxf(y, 0.f);
}

extern "C" void kernel_launch(void* const* d_in, const int* in_sizes, int n_in,
                              void* d_out, int out_size, void* d_ws, size_t ws_size,
                              hipStream_t stream) {
    const float* x       = (const float*)d_in[0];
    const int*   ei      = (const int*)d_in[1];
    const float* W_lin   = (const float*)d_in[2];
    const float* b_lin   = (const float*)d_in[3];
    const float* prelu_w = (const float*)d_in[4];
    const float* W_gat   = (const float*)d_in[5];
    const float* att_src = (const float*)d_in[6];
    const float* att_dst = (const float*)d_in[7];
    // d_in[8] = gat_bias: constant per-channel shift cancelled exactly by BN
    // mean-subtraction -> skipped.
    const float* bn_gamma = (const float*)d_in[9];
    const float* bn_beta  = (const float*)d_in[10];
    float* out = (float*)d_out;

    const int N = in_sizes[0] / D;
    const int E = in_sizes[1] / 2;

    // workspace carve-up (all chunk sizes multiples of 16B).
    // sums + deg8 + gcount are CONTIGUOUS so one hipMemsetAsync zeroes all.
    char* wp = (char*)d_ws;
    _Float16* hh = (_Float16*)wp;      wp += (size_t)N * D * H * sizeof(_Float16);
    float* asrc  = (float*)wp;          wp += (size_t)N * H * sizeof(float);
    float* adst  = (float*)wp;          wp += (size_t)N * H * sizeof(float);
    char* zero_base = wp;
    float* sums  = (float*)wp;          wp += 2 * D * sizeof(float);
    int* deg8    = (int*)wp;            wp += (size_t)8 * N * sizeof(int);
    int* gcount  = (int*)wp;            wp += 4 * sizeof(int);
    size_t zero_bytes = (size_t)(wp - zero_base);
    int* pref8   = (int*)wp;            wp += (size_t)8 * N * sizeof(int);
    int* deg     = (int*)wp;            wp += (size_t)N * sizeof(int);
    int* offs    = (int*)wp;            wp += (size_t)N * sizeof(int);
    int* rank    = (int*)wp;            wp += (size_t)E * sizeof(int);
    i32x4* recs  = (i32x4*)wp;          wp += ((size_t)E + 4) * sizeof(i32x4);
    (void)ws_size; (void)n_in; (void)out_size;

    const int total = N * D;
    const int NB = (N + 255) / 256;

    hipMemsetAsync(zero_base, 0, zero_bytes, stream);
    hipLaunchKernelGGL(k_node, dim3((N + 31) / 32), dim3(256), 0, stream,
                       x, W_lin, b_lin, prelu_w, W_gat, att_src, att_dst,
                       hh, asrc, adst, ei, deg8, rank, N, E);
    hipLaunchKernelGGL(k_offsets, dim3(NB), dim3(256), 0, stream,
                       deg8, pref8, deg, gcount, offs, N);
    hipLaunchKernelGGL(k_fill, dim3((E + 255) / 256), dim3(256), 0, stream,
                       ei, offs, pref8, rank, asrc, adst, recs, N, E);
    hipLaunchKernelGGL(k_agg, dim3((N + 3) / 4), dim3(256), 0, stream,
                       asrc, adst, offs, deg, recs, (const half4_t*)hh, out, N);
    hipLaunchKernelGGL(k_bn_stats, dim3(1024), dim3(256), 0, stream,
                       out, sums, total);
    hipLaunchKernelGGL(k_bn_apply, dim3((total + 255) / 256), dim3(256), 0, stream,
                       out, sums, bn_gamma, bn_beta, total, 1.f / (float)N);
}